// Round 14
// baseline (486.309 us; speedup 1.0000x reference)
//
#include <hip/hip_runtime.h>
#include <hip/hip_bf16.h>

// GCN classifier: N=100000, E=1.6M, IN=64, HID=128, 64 graphs, 2 classes.
// Round 14: 4-nodes-per-wave gathers (16-lane group per node; one load instr
// = 4 rows; 32 rows in flight per wave), uint2-widened stats/pool passes.

#define HID 128
#define NGRAPH 64
#define EPSN 1e-5f
#define BSHIFT 8            // 256 nodes per bucket
#define NBMAX 512

typedef unsigned int uint;
typedef unsigned short ushort;
typedef __attribute__((ext_vector_type(8))) short short8;   // 8 bf16 (4 VGPRs)
typedef __attribute__((ext_vector_type(4))) float f32x4;    // MFMA accumulator

static __device__ __forceinline__ ushort f2bf(float f) {  // round-nearest-even
  uint x = __float_as_uint(f);
  return (ushort)((x + 0x7FFFu + ((x >> 16) & 1u)) >> 16);
}
static __device__ __forceinline__ uint pack2(float a, float b) {
  return (uint)f2bf(a) | ((uint)f2bf(b) << 16);
}
static __device__ __forceinline__ float bf_lo(uint u) { return __uint_as_float(u << 16); }
static __device__ __forceinline__ float bf_hi(uint u) {
  return __uint_as_float(u & 0xFFFF0000u);
}

// ---------------- per-graph segment boundaries (batch sorted) ----------------
__global__ __launch_bounds__(256) void graph_starts(const int* __restrict__ batch,
                                                    int* __restrict__ gstart, int N) {
  int i = blockIdx.x * 256 + threadIdx.x;
  if (i >= N) return;
  int g = batch[i];
  if (i == 0) {
    for (int q = 0; q <= g; ++q) gstart[q] = 0;
  } else {
    int gp = batch[i - 1];
    if (g != gp)
      for (int q = gp + 1; q <= g; ++q) gstart[q] = i;
  }
  if (i == N - 1)
    for (int q = g + 1; q <= NGRAPH; ++q) gstart[q] = N;
}

// ---------------- padded-bucket counting sort: CSR build ----------------
// packed record: (src << 8) | (dst & 255)   [src < 2^24]
// gcursor is RELATIVE (zeroed by memset); absolute base = bucket*cap.
__global__ __launch_bounds__(256) void bin_edges(const int* __restrict__ src,
                                                 const int* __restrict__ dst,
                                                 int* __restrict__ gcursor,
                                                 uint* __restrict__ records, int E, int NB,
                                                 int cap) {
  __shared__ int h[NBMAX];
  __shared__ int base[NBMAX];
  for (int i = threadIdx.x; i < NB; i += 256) h[i] = 0;
  __syncthreads();
  int e0 = blockIdx.x * 4096;
  int d[16], s[16];
#pragma unroll
  for (int k = 0; k < 16; ++k) {
    int e = e0 + k * 256 + threadIdx.x;
    if (e < E) {
      d[k] = dst[e];
      s[k] = src[e];
      atomicAdd(&h[d[k] >> BSHIFT], 1);
    }
  }
  __syncthreads();
  for (int i = threadIdx.x; i < NB; i += 256) {
    int c = h[i];
    if (c) base[i] = i * cap + atomicAdd(&gcursor[i], c);
  }
  __syncthreads();
  for (int i = threadIdx.x; i < NB; i += 256) h[i] = 0;  // reuse as local cursor
  __syncthreads();
#pragma unroll
  for (int k = 0; k < 16; ++k) {
    int e = e0 + k * 256 + threadIdx.x;
    if (e < E) {
      int b = d[k] >> BSHIFT;
      int lp = atomicAdd(&h[b], 1);
      records[base[b] + lp] = ((uint)s[k] << 8) | (uint)(d[k] & 255);
    }
  }
}

// one block per bucket: local count/scan -> row_beg/row_end, dis, esrc (padded).
__global__ __launch_bounds__(256) void build_csr(const uint* __restrict__ records,
                                                 const int* __restrict__ gcursor,
                                                 int* __restrict__ row_beg,
                                                 int* __restrict__ row_end,
                                                 float* __restrict__ dis,
                                                 int* __restrict__ esrc, int N, int cap) {
  const int b = blockIdx.x;
  const int node0 = b << BSHIFT;
  const int nn = min(256, N - node0);
  const int beg = b * cap;
  const int cnt = gcursor[b];  // relative count
  const int t = threadIdx.x;
  __shared__ int lc[256], sc[256], lcur[256];
  lc[t] = 0;
  __syncthreads();
  for (int i = t; i < cnt; i += 256) atomicAdd(&lc[records[beg + i] & 255u], 1);
  __syncthreads();
  int myc = lc[t];
  sc[t] = myc;
  __syncthreads();
  for (int off = 1; off < 256; off <<= 1) {
    int add = (t >= off) ? sc[t - off] : 0;
    __syncthreads();
    sc[t] += add;
    __syncthreads();
  }
  int excl = sc[t] - myc;
  if (t < nn) {
    row_beg[node0 + t] = beg + excl;
    row_end[node0 + t] = beg + excl + myc;
    dis[node0 + t] = rsqrtf((float)myc + 1.0f);  // +1 self-loop
  }
  lcur[t] = excl;
  __syncthreads();
  for (int i = t; i < cnt; i += 256) {
    uint r = records[beg + i];
    int p = atomicAdd(&lcur[r & 255u], 1);
    esrc[beg + p] = (int)(r >> 8);
  }
}

// ---------------- xs = bf16(x * dis[row]) ----------------
__global__ __launch_bounds__(256) void xscale_bf16(const float* __restrict__ X,
                                                   const float* __restrict__ dis,
                                                   ushort* __restrict__ XS, int n4) {
  int i4 = blockIdx.x * 256 + threadIdx.x;  // unit = float4
  if (i4 >= n4) return;
  int n = i4 >> 4;  // 16 float4 per 64-ch row
  float dn = dis[n];
  float4 v = ((const float4*)X)[i4];
  ushort4 u;
  u.x = f2bf(v.x * dn);
  u.y = f2bf(v.y * dn);
  u.z = f2bf(v.z * dn);
  u.w = f2bf(v.w * dn);
  ((ushort4*)XS)[i4] = u;
}

// ---------------- both weight transposes: W (Kx128 f32) -> Wt (128xK bf16) ----------------
__global__ __launch_bounds__(256) void wt_both(const float* __restrict__ W1,
                                               const float* __restrict__ W2,
                                               ushort* __restrict__ w1t,
                                               ushort* __restrict__ w2t) {
  int i = blockIdx.x * 256 + threadIdx.x;
  if (i < 128 * 64) {
    int c = i / 64, k = i - c * 64;
    w1t[i] = f2bf(W1[(size_t)k * HID + c]);
  } else {
    int i2 = i - 128 * 64;
    if (i2 < 128 * 128) {
      int c = i2 / 128, k = i2 - c * 128;
      w2t[i2] = f2bf(W2[(size_t)k * HID + c]);
    }
  }
}

// ---------------- aggregate 64-ch bf16, 4 nodes/wave, 8-edge unroll ----------------
// 16-lane group per node: lane j=l&15 holds uint2 (4 ch); one load = 4 rows.
__global__ __launch_bounds__(256) void aggregate64(const ushort* __restrict__ XS,
                                                   const int* __restrict__ row_beg,
                                                   const int* __restrict__ row_end,
                                                   const int* __restrict__ esrc,
                                                   const float* __restrict__ dis,
                                                   ushort* __restrict__ out, int N) {
  int wave = (int)((blockIdx.x * 256 + threadIdx.x) >> 6);
  const int l = threadIdx.x & 63;
  const int n = wave * 4 + (l >> 4);
  if (n >= N) return;
  const int j = l & 15;  // uint2 slot: channels 4j..4j+3
  const float dn = dis[n];
  const int beg = row_beg[n];
  const int len = row_end[n] - beg;
  const uint2* Xj = (const uint2*)XS + j;  // row stride 16 uint2 (128B)
  float a0 = 0.f, a1 = 0.f, a2 = 0.f, a3 = 0.f;
  float b0 = 0.f, b1 = 0.f, b2 = 0.f, b3 = 0.f;
  int i = 0;
  for (; i + 7 < len; i += 8) {
    int s0 = esrc[beg + i], s1 = esrc[beg + i + 1];
    int s2 = esrc[beg + i + 2], s3 = esrc[beg + i + 3];
    int s4 = esrc[beg + i + 4], s5 = esrc[beg + i + 5];
    int s6 = esrc[beg + i + 6], s7 = esrc[beg + i + 7];
    uint2 u0 = Xj[(size_t)s0 * 16];
    uint2 u1 = Xj[(size_t)s1 * 16];
    uint2 u2 = Xj[(size_t)s2 * 16];
    uint2 u3 = Xj[(size_t)s3 * 16];
    uint2 u4 = Xj[(size_t)s4 * 16];
    uint2 u5 = Xj[(size_t)s5 * 16];
    uint2 u6 = Xj[(size_t)s6 * 16];
    uint2 u7 = Xj[(size_t)s7 * 16];
    a0 += bf_lo(u0.x) + bf_lo(u1.x) + bf_lo(u2.x) + bf_lo(u3.x);
    a1 += bf_hi(u0.x) + bf_hi(u1.x) + bf_hi(u2.x) + bf_hi(u3.x);
    a2 += bf_lo(u0.y) + bf_lo(u1.y) + bf_lo(u2.y) + bf_lo(u3.y);
    a3 += bf_hi(u0.y) + bf_hi(u1.y) + bf_hi(u2.y) + bf_hi(u3.y);
    b0 += bf_lo(u4.x) + bf_lo(u5.x) + bf_lo(u6.x) + bf_lo(u7.x);
    b1 += bf_hi(u4.x) + bf_hi(u5.x) + bf_hi(u6.x) + bf_hi(u7.x);
    b2 += bf_lo(u4.y) + bf_lo(u5.y) + bf_lo(u6.y) + bf_lo(u7.y);
    b3 += bf_hi(u4.y) + bf_hi(u5.y) + bf_hi(u6.y) + bf_hi(u7.y);
  }
  for (; i < len; ++i) {
    uint2 u = Xj[(size_t)esrc[beg + i] * 16];
    a0 += bf_lo(u.x);
    a1 += bf_hi(u.x);
    a2 += bf_lo(u.y);
    a3 += bf_hi(u.y);
  }
  uint2 us = Xj[(size_t)n * 16];  // self (prescaled)
  a0 += b0 + bf_lo(us.x);
  a1 += b1 + bf_hi(us.x);
  a2 += b2 + bf_lo(us.y);
  a3 += b3 + bf_hi(us.y);
  uint2 o;
  o.x = pack2(a0 * dn, a1 * dn);
  o.y = pack2(a2 * dn, a3 * dn);
  ((uint2*)out)[(size_t)n * 16 + j] = o;
}

// ---------------- aggregate 128-ch bf16 + bias, 4 nodes/wave, 8-edge unroll ----------------
// 16-lane group per node: lane j=l&15 holds uint4 (8 ch); one load = 4 rows.
__global__ __launch_bounds__(256) void aggregate128(const ushort* __restrict__ H,
                                                    const int* __restrict__ row_beg,
                                                    const int* __restrict__ row_end,
                                                    const int* __restrict__ esrc,
                                                    const float* __restrict__ dis,
                                                    const float* __restrict__ bias,
                                                    ushort* __restrict__ outz, int N) {
  int wave = (int)((blockIdx.x * 256 + threadIdx.x) >> 6);
  const int l = threadIdx.x & 63;
  const int n = wave * 4 + (l >> 4);
  if (n >= N) return;
  const int j = l & 15;  // uint4 slot: channels 8j..8j+7
  const float dn = dis[n];
  const int beg = row_beg[n];
  const int len = row_end[n] - beg;
  const uint4* Hj = (const uint4*)H + j;  // row stride 16 uint4 (256B)
  float a0 = 0.f, a1 = 0.f, a2 = 0.f, a3 = 0.f;
  float a4 = 0.f, a5 = 0.f, a6 = 0.f, a7 = 0.f;
  float b0 = 0.f, b1 = 0.f, b2 = 0.f, b3 = 0.f;
  float b4 = 0.f, b5 = 0.f, b6 = 0.f, b7 = 0.f;
  int i = 0;
  for (; i + 7 < len; i += 8) {
    int s0 = esrc[beg + i], s1 = esrc[beg + i + 1];
    int s2 = esrc[beg + i + 2], s3 = esrc[beg + i + 3];
    int s4 = esrc[beg + i + 4], s5 = esrc[beg + i + 5];
    int s6 = esrc[beg + i + 6], s7 = esrc[beg + i + 7];
    uint4 u0 = Hj[(size_t)s0 * 16];
    uint4 u1 = Hj[(size_t)s1 * 16];
    uint4 u2 = Hj[(size_t)s2 * 16];
    uint4 u3 = Hj[(size_t)s3 * 16];
    uint4 u4 = Hj[(size_t)s4 * 16];
    uint4 u5 = Hj[(size_t)s5 * 16];
    uint4 u6 = Hj[(size_t)s6 * 16];
    uint4 u7 = Hj[(size_t)s7 * 16];
    a0 += bf_lo(u0.x) + bf_lo(u1.x) + bf_lo(u2.x) + bf_lo(u3.x);
    a1 += bf_hi(u0.x) + bf_hi(u1.x) + bf_hi(u2.x) + bf_hi(u3.x);
    a2 += bf_lo(u0.y) + bf_lo(u1.y) + bf_lo(u2.y) + bf_lo(u3.y);
    a3 += bf_hi(u0.y) + bf_hi(u1.y) + bf_hi(u2.y) + bf_hi(u3.y);
    a4 += bf_lo(u0.z) + bf_lo(u1.z) + bf_lo(u2.z) + bf_lo(u3.z);
    a5 += bf_hi(u0.z) + bf_hi(u1.z) + bf_hi(u2.z) + bf_hi(u3.z);
    a6 += bf_lo(u0.w) + bf_lo(u1.w) + bf_lo(u2.w) + bf_lo(u3.w);
    a7 += bf_hi(u0.w) + bf_hi(u1.w) + bf_hi(u2.w) + bf_hi(u3.w);
    b0 += bf_lo(u4.x) + bf_lo(u5.x) + bf_lo(u6.x) + bf_lo(u7.x);
    b1 += bf_hi(u4.x) + bf_hi(u5.x) + bf_hi(u6.x) + bf_hi(u7.x);
    b2 += bf_lo(u4.y) + bf_lo(u5.y) + bf_lo(u6.y) + bf_lo(u7.y);
    b3 += bf_hi(u4.y) + bf_hi(u5.y) + bf_hi(u6.y) + bf_hi(u7.y);
    b4 += bf_lo(u4.z) + bf_lo(u5.z) + bf_lo(u6.z) + bf_lo(u7.z);
    b5 += bf_hi(u4.z) + bf_hi(u5.z) + bf_hi(u6.z) + bf_hi(u7.z);
    b6 += bf_lo(u4.w) + bf_lo(u5.w) + bf_lo(u6.w) + bf_lo(u7.w);
    b7 += bf_hi(u4.w) + bf_hi(u5.w) + bf_hi(u6.w) + bf_hi(u7.w);
  }
  for (; i < len; ++i) {
    uint4 u = Hj[(size_t)esrc[beg + i] * 16];
    a0 += bf_lo(u.x);
    a1 += bf_hi(u.x);
    a2 += bf_lo(u.y);
    a3 += bf_hi(u.y);
    a4 += bf_lo(u.z);
    a5 += bf_hi(u.z);
    a6 += bf_lo(u.w);
    a7 += bf_hi(u.w);
  }
  uint4 us = Hj[(size_t)n * 16];  // self (prescaled)
  a0 += b0 + bf_lo(us.x);
  a1 += b1 + bf_hi(us.x);
  a2 += b2 + bf_lo(us.y);
  a3 += b3 + bf_hi(us.y);
  a4 += b4 + bf_lo(us.z);
  a5 += b5 + bf_hi(us.z);
  a6 += b6 + bf_lo(us.w);
  a7 += b7 + bf_hi(us.w);
  float4 bv0 = ((const float4*)bias)[2 * j];
  float4 bv1 = ((const float4*)bias)[2 * j + 1];
  uint4 o;
  o.x = pack2(a0 * dn + bv0.x, a1 * dn + bv0.y);
  o.y = pack2(a2 * dn + bv0.z, a3 * dn + bv0.w);
  o.z = pack2(a4 * dn + bv1.x, a5 * dn + bv1.y);
  o.w = pack2(a6 * dn + bv1.z, a7 * dn + bv1.w);
  ((uint4*)outz)[(size_t)n * 16 + j] = o;
}

// ---------------- MFMA GEMM: Y[N][128] = bf16X[N][K] @ W[K][128] -> bf16 ----------------
template <int K, bool FUSE_NORM, bool DIS_SCALE, bool HAS_BIAS>
__global__ __launch_bounds__(256) void gemm_mfma(const ushort* __restrict__ X,
                                                 const ushort* __restrict__ Wt,
                                                 const float* __restrict__ bias,
                                                 const int* __restrict__ batch,
                                                 const float* __restrict__ mean,
                                                 const float* __restrict__ inv,
                                                 const float* __restrict__ disv,
                                                 ushort* __restrict__ Y, int N) {
  const int t = threadIdx.x;
  const int w = t >> 6;
  const int l = t & 63;
  const int lr = l & 15;   // A row / B-D col within tile
  const int lk = l >> 4;   // k-group 0..3 (also D row group)
  const int row0 = blockIdx.x * 64 + w * 16;
  const int arow = min(row0 + lr, N - 1);  // clamp: OOB rows produce discarded C rows
  int g = 0;
  if (FUSE_NORM) g = batch[arow];
  f32x4 acc[8];
#pragma unroll
  for (int i = 0; i < 8; ++i) acc[i] = (f32x4){0.f, 0.f, 0.f, 0.f};
#pragma unroll
  for (int k0 = 0; k0 < K; k0 += 32) {
    const int kbase = k0 + lk * 8;
    short8 a = *(const short8*)(X + (size_t)arow * K + kbase);
    if (FUSE_NORM) {
      const float* mp = mean + g * HID + kbase;
      const float* ip = inv + g * HID + kbase;
      short8 an;
#pragma unroll
      for (int j = 0; j < 8; ++j) {
        float f = __uint_as_float((uint)(ushort)a[j] << 16);
        f = fmaxf((f - mp[j]) * ip[j], 0.f);
        an[j] = (short)f2bf(f);
      }
      a = an;
    }
#pragma unroll
    for (int nf = 0; nf < 8; ++nf) {
      short8 b = *(const short8*)(Wt + (size_t)(nf * 16 + lr) * K + kbase);
      acc[nf] = __builtin_amdgcn_mfma_f32_16x16x32_bf16(a, b, acc[nf], 0, 0, 0);
    }
  }
#pragma unroll
  for (int r = 0; r < 4; ++r) {
    int grow = row0 + lk * 4 + r;
    if (grow < N) {
      float ds = DIS_SCALE ? disv[grow] : 1.f;
#pragma unroll
      for (int nf = 0; nf < 8; ++nf) {
        int col = nf * 16 + lr;
        float v = acc[nf][r];
        if (HAS_BIAS) v += bias[col];
        v *= ds;
        Y[(size_t)grow * HID + col] = f2bf(v);
      }
    }
  }
}

// ---------------- per-graph sum/sumsq (bf16 input, uint2 loads) ----------------
__global__ __launch_bounds__(256) void stats_pass(const ushort* __restrict__ G,
                                                  const int* __restrict__ batch,
                                                  float* __restrict__ gsum,
                                                  float* __restrict__ gsq, int N) {
  const int c4 = threadIdx.x & 31;   // uint2 slot: ch 4c4..4c4+3
  const int sub = threadIdx.x >> 5;  // 0..7
  const int n0 = blockIdx.x * 64 + sub * 8;
  const int n1 = min(n0 + 8, N);
  const uint2* Gj = (const uint2*)G + c4;  // row stride 32 uint2
  float s0 = 0.f, s1 = 0.f, s2 = 0.f, s3 = 0.f;
  float q0 = 0.f, q1 = 0.f, q2 = 0.f, q3 = 0.f;
  int cur = -1;
  for (int n = n0; n < n1; ++n) {
    int g = batch[n];
    if (g != cur) {
      if (cur >= 0) {
        float* gs = gsum + cur * HID + 4 * c4;
        float* gq = gsq + cur * HID + 4 * c4;
        atomicAdd(gs + 0, s0);
        atomicAdd(gs + 1, s1);
        atomicAdd(gs + 2, s2);
        atomicAdd(gs + 3, s3);
        atomicAdd(gq + 0, q0);
        atomicAdd(gq + 1, q1);
        atomicAdd(gq + 2, q2);
        atomicAdd(gq + 3, q3);
      }
      cur = g;
      s0 = s1 = s2 = s3 = 0.f;
      q0 = q1 = q2 = q3 = 0.f;
    }
    uint2 u = Gj[(size_t)n * 32];
    float v0 = bf_lo(u.x), v1 = bf_hi(u.x), v2 = bf_lo(u.y), v3 = bf_hi(u.y);
    s0 += v0;
    s1 += v1;
    s2 += v2;
    s3 += v3;
    q0 += v0 * v0;
    q1 += v1 * v1;
    q2 += v2 * v2;
    q3 += v3 * v3;
  }
  if (cur >= 0) {
    float* gs = gsum + cur * HID + 4 * c4;
    float* gq = gsq + cur * HID + 4 * c4;
    atomicAdd(gs + 0, s0);
    atomicAdd(gs + 1, s1);
    atomicAdd(gs + 2, s2);
    atomicAdd(gs + 3, s3);
    atomicAdd(gq + 0, q0);
    atomicAdd(gq + 1, q1);
    atomicAdd(gq + 2, q2);
    atomicAdd(gq + 3, q3);
  }
}

__global__ __launch_bounds__(256) void finalize_stats(const float* __restrict__ gsum,
                                                      const float* __restrict__ gsq,
                                                      const int* __restrict__ gstart,
                                                      float* __restrict__ mean,
                                                      float* __restrict__ inv) {
  int i = blockIdx.x * 256 + threadIdx.x;
  if (i >= NGRAPH * HID) return;
  int g = i >> 7;
  float c = fmaxf((float)(gstart[g + 1] - gstart[g]), 1.f);
  float m = gsum[i] / c;
  float v = gsq[i] / c - m * m;
  mean[i] = m;
  inv[i] = rsqrtf(v + EPSN);
}

// ---------------- norm+relu+pool (bf16 input, uint2 loads) ----------------
__global__ __launch_bounds__(256) void norm_relu_pool(const ushort* __restrict__ G,
                                                      const int* __restrict__ batch,
                                                      const float* __restrict__ mean,
                                                      const float* __restrict__ inv,
                                                      float* __restrict__ pooled, int N) {
  const int c4 = threadIdx.x & 31;
  const int sub = threadIdx.x >> 5;
  const int n0 = blockIdx.x * 64 + sub * 8;
  const int n1 = min(n0 + 8, N);
  const uint2* Gj = (const uint2*)G + c4;
  float p0 = 0.f, p1 = 0.f, p2 = 0.f, p3 = 0.f;
  int cur = -1;
  float4 mv = {0.f, 0.f, 0.f, 0.f}, iv = {0.f, 0.f, 0.f, 0.f};
  for (int n = n0; n < n1; ++n) {
    int g = batch[n];
    if (g != cur) {
      if (cur >= 0) {
        float* pp = pooled + cur * HID + 4 * c4;
        atomicAdd(pp + 0, p0);
        atomicAdd(pp + 1, p1);
        atomicAdd(pp + 2, p2);
        atomicAdd(pp + 3, p3);
      }
      cur = g;
      p0 = p1 = p2 = p3 = 0.f;
      mv = ((const float4*)mean)[g * 32 + c4];
      iv = ((const float4*)inv)[g * 32 + c4];
    }
    uint2 u = Gj[(size_t)n * 32];
    p0 += fmaxf((bf_lo(u.x) - mv.x) * iv.x, 0.f);
    p1 += fmaxf((bf_hi(u.x) - mv.y) * iv.y, 0.f);
    p2 += fmaxf((bf_lo(u.y) - mv.z) * iv.z, 0.f);
    p3 += fmaxf((bf_hi(u.y) - mv.w) * iv.w, 0.f);
  }
  if (cur >= 0) {
    float* pp = pooled + cur * HID + 4 * c4;
    atomicAdd(pp + 0, p0);
    atomicAdd(pp + 1, p1);
    atomicAdd(pp + 2, p2);
    atomicAdd(pp + 3, p3);
  }
}

// ---------------- final head ----------------
__global__ __launch_bounds__(256) void final_head(const float* __restrict__ pooled_sum,
                                                  const int* __restrict__ gstart,
                                                  const float* __restrict__ gamma,
                                                  const float* __restrict__ beta,
                                                  const float* __restrict__ fcW,
                                                  const float* __restrict__ fcb,
                                                  float* __restrict__ out) {
  __shared__ float P[NGRAPH][HID];
  __shared__ float zs[HID], zb[HID];
  int t = threadIdx.x;
  for (int i = t; i < NGRAPH * HID; i += 256) {
    int g = i >> 7;
    float c = fmaxf((float)(gstart[g + 1] - gstart[g]), 1.f);
    P[g][i & 127] = pooled_sum[i] / c;
  }
  __syncthreads();
  if (t < HID) {
    float m = 0.f;
    for (int g = 0; g < NGRAPH; ++g) m += P[g][t];
    m *= (1.f / NGRAPH);
    float v = 0.f;
    for (int g = 0; g < NGRAPH; ++g) {
      float d = P[g][t] - m;
      v += d * d;
    }
    v *= (1.f / NGRAPH);
    float sc = rsqrtf(v + EPSN) * gamma[t];
    zs[t] = sc;
    zb[t] = beta[t] - m * sc;
  }
  __syncthreads();
  if (t < NGRAPH * 2) {
    int g = t >> 1, k = t & 1;
    float acc = fcb[k];
    for (int c = 0; c < HID; ++c) {
      float z = P[g][c] * zs[c] + zb[c];
      acc += z * fcW[c * 2 + k];
    }
    out[t] = acc;
  }
}

extern "C" void kernel_launch(void* const* d_in, const int* in_sizes, int n_in,
                              void* d_out, int out_size, void* d_ws, size_t ws_size,
                              hipStream_t stream) {
  const float* x = (const float*)d_in[0];
  const int* ei = (const int*)d_in[1];     // int32
  const int* batch = (const int*)d_in[2];  // int32 (sorted)
  const float* W1 = (const float*)d_in[3];
  const float* b1 = (const float*)d_in[4];
  const float* W2 = (const float*)d_in[5];
  const float* b2 = (const float*)d_in[6];
  const float* gamma = (const float*)d_in[7];
  const float* beta = (const float*)d_in[8];
  const float* fcW = (const float*)d_in[9];
  const float* fcb = (const float*)d_in[10];
  float* out = (float*)d_out;

  const int N = in_sizes[2];
  const int E = in_sizes[1] / 2;
  const int* srcp = ei;
  const int* dstp = ei + E;
  const int NB = (N + 255) >> BSHIFT;       // buckets (<=512 for N<=131072)
  const int cap = 2 * (E / NB) + 256;       // per-bucket capacity (~64 sigma margin)

  // workspace layout (floats)
  float* ws = (float*)d_ws;
  size_t off = 0;
  auto alloc = [&](size_t n) {
    float* p = ws + off;
    off += (n + 127) & ~(size_t)127;
    return p;
  };
  int* row_beg = (int*)alloc(N);
  int* row_end = (int*)alloc(N);
  int* esrc = (int*)alloc((size_t)NB * cap);
  // records (NB*cap uints) region, later reused as xs (bf16 N x 64 = N*32 uints)
  size_t recsz = ((size_t)NB * cap > (size_t)N * 32 ? (size_t)NB * cap : (size_t)N * 32);
  float* recbuf = alloc(recsz);
  float* dis = alloc(N);
  float* y1b = alloc((size_t)N * 32);   // bf16 N x 64
  float* h1b = alloc((size_t)N * 64);   // bf16 N x 128
  float* h2b = alloc((size_t)N * 64);   // bf16 N x 128
  float* zb_ = alloc((size_t)N * 64);   // bf16 N x 128
  float* w1tb = alloc(128 * 64 / 2);    // bf16 128x64 (col-major Wt)
  float* w2tb = alloc(128 * 128 / 2);   // bf16 128x128
  int* gstart = (int*)alloc(NGRAPH + 1);
  float* zero0 = ws + off;              // zeroed region start
  int* gcursor = (int*)alloc(NBMAX);    // relative cursors (must be zeroed)
  float* gsum1 = alloc(NGRAPH * HID);
  float* gsq1 = alloc(NGRAPH * HID);
  float* gsum2 = alloc(NGRAPH * HID);
  float* gsq2 = alloc(NGRAPH * HID);
  float* pooled = alloc(NGRAPH * HID);
  size_t zero_bytes = (size_t)((ws + off) - zero0) * sizeof(float);
  float* mean1 = alloc(NGRAPH * HID);
  float* inv1 = alloc(NGRAPH * HID);
  float* mean2 = alloc(NGRAPH * HID);
  float* inv2 = alloc(NGRAPH * HID);

  uint* records = (uint*)recbuf;
  ushort* xs = (ushort*)recbuf;  // alias: records dead after build_csr
  ushort* y1 = (ushort*)y1b;
  ushort* h1 = (ushort*)h1b;
  ushort* h2s = (ushort*)h2b;
  ushort* z = (ushort*)zb_;
  ushort* w1t = (ushort*)w1tb;
  ushort* w2t = (ushort*)w2tb;

  const int nblkN = (N + 255) / 256;
  const int nblkE4k = (E + 4095) / 4096;

  hipMemsetAsync(zero0, 0, zero_bytes, stream);

  // weight transposes + graph segments + padded CSR build
  wt_both<<<(128 * 64 + 128 * 128 + 255) / 256, 256, 0, stream>>>(W1, W2, w1t, w2t);
  graph_starts<<<nblkN, 256, 0, stream>>>(batch, gstart, N);
  bin_edges<<<nblkE4k, 256, 0, stream>>>(srcp, dstp, gcursor, records, E, NB, cap);
  build_csr<<<NB, 256, 0, stream>>>(records, gcursor, row_beg, row_end, dis, esrc, N, cap);

  const int aggBlocks = ((N + 3) / 4 + 3) / 4;  // 4 nodes per wave, 4 waves/block
  const int gemmBlocks = (N + 63) / 64;         // 64 rows per block
  const int nrmBlocks = (N + 63) / 64;          // stats/pool: 64 nodes per block

  // ---- layer 1: xs = bf16(x*dis); y1 = A-hat x (bf16); h1 = y1 @ W1 + b1 (bf16) ----
  xscale_bf16<<<(N * 16 + 255) / 256, 256, 0, stream>>>(x, dis, xs, N * 16);
  aggregate64<<<aggBlocks, 256, 0, stream>>>(xs, row_beg, row_end, esrc, dis, y1, N);
  gemm_mfma<64, false, false, true><<<gemmBlocks, 256, 0, stream>>>(
      y1, w1t, b1, nullptr, nullptr, nullptr, nullptr, h1, N);
  stats_pass<<<nrmBlocks, 256, 0, stream>>>(h1, batch, gsum1, gsq1, N);
  finalize_stats<<<(NGRAPH * HID + 255) / 256, 256, 0, stream>>>(gsum1, gsq1, gstart, mean1, inv1);

  // ---- layer 2: h2s = bf16(relu(norm(h1)) @ W2 * dis); z = A-hat h2 + b2 (bf16) ----
  gemm_mfma<128, true, true, false><<<gemmBlocks, 256, 0, stream>>>(
      h1, w2t, nullptr, batch, mean1, inv1, dis, h2s, N);
  aggregate128<<<aggBlocks, 256, 0, stream>>>(h2s, row_beg, row_end, esrc, dis, b2, z, N);
  stats_pass<<<nrmBlocks, 256, 0, stream>>>(z, batch, gsum2, gsq2, N);
  finalize_stats<<<(NGRAPH * HID + 255) / 256, 256, 0, stream>>>(gsum2, gsq2, gstart, mean2, inv2);
  norm_relu_pool<<<nrmBlocks, 256, 0, stream>>>(z, batch, mean2, inv2, pooled, N);

  // ---- head ----
  final_head<<<1, 256, 0, stream>>>(pooled, gstart, gamma, beta, fcW, fcb, out);
}

// Round 15
// 295.465 us; speedup vs baseline: 1.6459x; 1.6459x over previous
//
#include <hip/hip_runtime.h>
#include <hip/hip_bf16.h>

// GCN classifier: N=100000, E=1.6M, IN=64, HID=128, 64 graphs, 2 classes.
// Round 15: revert round-14's widened stats/pool (8 atomics/flush doubled
// same-address contention: stats_pass 104us, VALUBusy 1.4%). Round-13 shape
// (2ch x 16 nodes, 4 atomics) + 4-way replica accumulators (blockIdx&3)
// to quarter per-address contention. Keep 4-nodes/wave gathers (good).

#define HID 128
#define NGRAPH 64
#define EPSN 1e-5f
#define BSHIFT 8            // 256 nodes per bucket
#define NBMAX 512
#define REP 4               // accumulator replicas
#define NH (NGRAPH * HID)

typedef unsigned int uint;
typedef unsigned short ushort;
typedef __attribute__((ext_vector_type(8))) short short8;   // 8 bf16 (4 VGPRs)
typedef __attribute__((ext_vector_type(4))) float f32x4;    // MFMA accumulator

static __device__ __forceinline__ ushort f2bf(float f) {  // round-nearest-even
  uint x = __float_as_uint(f);
  return (ushort)((x + 0x7FFFu + ((x >> 16) & 1u)) >> 16);
}
static __device__ __forceinline__ uint pack2(float a, float b) {
  return (uint)f2bf(a) | ((uint)f2bf(b) << 16);
}
static __device__ __forceinline__ float bf_lo(uint u) { return __uint_as_float(u << 16); }
static __device__ __forceinline__ float bf_hi(uint u) {
  return __uint_as_float(u & 0xFFFF0000u);
}

// ---------------- per-graph segment boundaries (batch sorted) ----------------
__global__ __launch_bounds__(256) void graph_starts(const int* __restrict__ batch,
                                                    int* __restrict__ gstart, int N) {
  int i = blockIdx.x * 256 + threadIdx.x;
  if (i >= N) return;
  int g = batch[i];
  if (i == 0) {
    for (int q = 0; q <= g; ++q) gstart[q] = 0;
  } else {
    int gp = batch[i - 1];
    if (g != gp)
      for (int q = gp + 1; q <= g; ++q) gstart[q] = i;
  }
  if (i == N - 1)
    for (int q = g + 1; q <= NGRAPH; ++q) gstart[q] = N;
}

// ---------------- padded-bucket counting sort: CSR build ----------------
// packed record: (src << 8) | (dst & 255)   [src < 2^24]
// gcursor is RELATIVE (zeroed by memset); absolute base = bucket*cap.
__global__ __launch_bounds__(256) void bin_edges(const int* __restrict__ src,
                                                 const int* __restrict__ dst,
                                                 int* __restrict__ gcursor,
                                                 uint* __restrict__ records, int E, int NB,
                                                 int cap) {
  __shared__ int h[NBMAX];
  __shared__ int base[NBMAX];
  for (int i = threadIdx.x; i < NB; i += 256) h[i] = 0;
  __syncthreads();
  int e0 = blockIdx.x * 4096;
  int d[16], s[16];
#pragma unroll
  for (int k = 0; k < 16; ++k) {
    int e = e0 + k * 256 + threadIdx.x;
    if (e < E) {
      d[k] = dst[e];
      s[k] = src[e];
      atomicAdd(&h[d[k] >> BSHIFT], 1);
    }
  }
  __syncthreads();
  for (int i = threadIdx.x; i < NB; i += 256) {
    int c = h[i];
    if (c) base[i] = i * cap + atomicAdd(&gcursor[i], c);
  }
  __syncthreads();
  for (int i = threadIdx.x; i < NB; i += 256) h[i] = 0;  // reuse as local cursor
  __syncthreads();
#pragma unroll
  for (int k = 0; k < 16; ++k) {
    int e = e0 + k * 256 + threadIdx.x;
    if (e < E) {
      int b = d[k] >> BSHIFT;
      int lp = atomicAdd(&h[b], 1);
      records[base[b] + lp] = ((uint)s[k] << 8) | (uint)(d[k] & 255);
    }
  }
}

// one block per bucket: local count/scan -> row_beg/row_end, dis, esrc (padded).
__global__ __launch_bounds__(256) void build_csr(const uint* __restrict__ records,
                                                 const int* __restrict__ gcursor,
                                                 int* __restrict__ row_beg,
                                                 int* __restrict__ row_end,
                                                 float* __restrict__ dis,
                                                 int* __restrict__ esrc, int N, int cap) {
  const int b = blockIdx.x;
  const int node0 = b << BSHIFT;
  const int nn = min(256, N - node0);
  const int beg = b * cap;
  const int cnt = gcursor[b];  // relative count
  const int t = threadIdx.x;
  __shared__ int lc[256], sc[256], lcur[256];
  lc[t] = 0;
  __syncthreads();
  for (int i = t; i < cnt; i += 256) atomicAdd(&lc[records[beg + i] & 255u], 1);
  __syncthreads();
  int myc = lc[t];
  sc[t] = myc;
  __syncthreads();
  for (int off = 1; off < 256; off <<= 1) {
    int add = (t >= off) ? sc[t - off] : 0;
    __syncthreads();
    sc[t] += add;
    __syncthreads();
  }
  int excl = sc[t] - myc;
  if (t < nn) {
    row_beg[node0 + t] = beg + excl;
    row_end[node0 + t] = beg + excl + myc;
    dis[node0 + t] = rsqrtf((float)myc + 1.0f);  // +1 self-loop
  }
  lcur[t] = excl;
  __syncthreads();
  for (int i = t; i < cnt; i += 256) {
    uint r = records[beg + i];
    int p = atomicAdd(&lcur[r & 255u], 1);
    esrc[beg + p] = (int)(r >> 8);
  }
}

// ---------------- xs = bf16(x * dis[row]) ----------------
__global__ __launch_bounds__(256) void xscale_bf16(const float* __restrict__ X,
                                                   const float* __restrict__ dis,
                                                   ushort* __restrict__ XS, int n4) {
  int i4 = blockIdx.x * 256 + threadIdx.x;  // unit = float4
  if (i4 >= n4) return;
  int n = i4 >> 4;  // 16 float4 per 64-ch row
  float dn = dis[n];
  float4 v = ((const float4*)X)[i4];
  ushort4 u;
  u.x = f2bf(v.x * dn);
  u.y = f2bf(v.y * dn);
  u.z = f2bf(v.z * dn);
  u.w = f2bf(v.w * dn);
  ((ushort4*)XS)[i4] = u;
}

// ---------------- both weight transposes: W (Kx128 f32) -> Wt (128xK bf16) ----------------
__global__ __launch_bounds__(256) void wt_both(const float* __restrict__ W1,
                                               const float* __restrict__ W2,
                                               ushort* __restrict__ w1t,
                                               ushort* __restrict__ w2t) {
  int i = blockIdx.x * 256 + threadIdx.x;
  if (i < 128 * 64) {
    int c = i / 64, k = i - c * 64;
    w1t[i] = f2bf(W1[(size_t)k * HID + c]);
  } else {
    int i2 = i - 128 * 64;
    if (i2 < 128 * 128) {
      int c = i2 / 128, k = i2 - c * 128;
      w2t[i2] = f2bf(W2[(size_t)k * HID + c]);
    }
  }
}

// ---------------- aggregate 64-ch bf16, 4 nodes/wave, 8-edge unroll ----------------
// 16-lane group per node: lane j=l&15 holds uint2 (4 ch); one load = 4 rows.
__global__ __launch_bounds__(256) void aggregate64(const ushort* __restrict__ XS,
                                                   const int* __restrict__ row_beg,
                                                   const int* __restrict__ row_end,
                                                   const int* __restrict__ esrc,
                                                   const float* __restrict__ dis,
                                                   ushort* __restrict__ out, int N) {
  int wave = (int)((blockIdx.x * 256 + threadIdx.x) >> 6);
  const int l = threadIdx.x & 63;
  const int n = wave * 4 + (l >> 4);
  if (n >= N) return;
  const int j = l & 15;  // uint2 slot: channels 4j..4j+3
  const float dn = dis[n];
  const int beg = row_beg[n];
  const int len = row_end[n] - beg;
  const uint2* Xj = (const uint2*)XS + j;  // row stride 16 uint2 (128B)
  float a0 = 0.f, a1 = 0.f, a2 = 0.f, a3 = 0.f;
  float b0 = 0.f, b1 = 0.f, b2 = 0.f, b3 = 0.f;
  int i = 0;
  for (; i + 7 < len; i += 8) {
    int s0 = esrc[beg + i], s1 = esrc[beg + i + 1];
    int s2 = esrc[beg + i + 2], s3 = esrc[beg + i + 3];
    int s4 = esrc[beg + i + 4], s5 = esrc[beg + i + 5];
    int s6 = esrc[beg + i + 6], s7 = esrc[beg + i + 7];
    uint2 u0 = Xj[(size_t)s0 * 16];
    uint2 u1 = Xj[(size_t)s1 * 16];
    uint2 u2 = Xj[(size_t)s2 * 16];
    uint2 u3 = Xj[(size_t)s3 * 16];
    uint2 u4 = Xj[(size_t)s4 * 16];
    uint2 u5 = Xj[(size_t)s5 * 16];
    uint2 u6 = Xj[(size_t)s6 * 16];
    uint2 u7 = Xj[(size_t)s7 * 16];
    a0 += bf_lo(u0.x) + bf_lo(u1.x) + bf_lo(u2.x) + bf_lo(u3.x);
    a1 += bf_hi(u0.x) + bf_hi(u1.x) + bf_hi(u2.x) + bf_hi(u3.x);
    a2 += bf_lo(u0.y) + bf_lo(u1.y) + bf_lo(u2.y) + bf_lo(u3.y);
    a3 += bf_hi(u0.y) + bf_hi(u1.y) + bf_hi(u2.y) + bf_hi(u3.y);
    b0 += bf_lo(u4.x) + bf_lo(u5.x) + bf_lo(u6.x) + bf_lo(u7.x);
    b1 += bf_hi(u4.x) + bf_hi(u5.x) + bf_hi(u6.x) + bf_hi(u7.x);
    b2 += bf_lo(u4.y) + bf_lo(u5.y) + bf_lo(u6.y) + bf_lo(u7.y);
    b3 += bf_hi(u4.y) + bf_hi(u5.y) + bf_hi(u6.y) + bf_hi(u7.y);
  }
  for (; i < len; ++i) {
    uint2 u = Xj[(size_t)esrc[beg + i] * 16];
    a0 += bf_lo(u.x);
    a1 += bf_hi(u.x);
    a2 += bf_lo(u.y);
    a3 += bf_hi(u.y);
  }
  uint2 us = Xj[(size_t)n * 16];  // self (prescaled)
  a0 += b0 + bf_lo(us.x);
  a1 += b1 + bf_hi(us.x);
  a2 += b2 + bf_lo(us.y);
  a3 += b3 + bf_hi(us.y);
  uint2 o;
  o.x = pack2(a0 * dn, a1 * dn);
  o.y = pack2(a2 * dn, a3 * dn);
  ((uint2*)out)[(size_t)n * 16 + j] = o;
}

// ---------------- aggregate 128-ch bf16 + bias, 4 nodes/wave, 8-edge unroll ----------------
// 16-lane group per node: lane j=l&15 holds uint4 (8 ch); one load = 4 rows.
__global__ __launch_bounds__(256) void aggregate128(const ushort* __restrict__ H,
                                                    const int* __restrict__ row_beg,
                                                    const int* __restrict__ row_end,
                                                    const int* __restrict__ esrc,
                                                    const float* __restrict__ dis,
                                                    const float* __restrict__ bias,
                                                    ushort* __restrict__ outz, int N) {
  int wave = (int)((blockIdx.x * 256 + threadIdx.x) >> 6);
  const int l = threadIdx.x & 63;
  const int n = wave * 4 + (l >> 4);
  if (n >= N) return;
  const int j = l & 15;  // uint4 slot: channels 8j..8j+7
  const float dn = dis[n];
  const int beg = row_beg[n];
  const int len = row_end[n] - beg;
  const uint4* Hj = (const uint4*)H + j;  // row stride 16 uint4 (256B)
  float a0 = 0.f, a1 = 0.f, a2 = 0.f, a3 = 0.f;
  float a4 = 0.f, a5 = 0.f, a6 = 0.f, a7 = 0.f;
  float b0 = 0.f, b1 = 0.f, b2 = 0.f, b3 = 0.f;
  float b4 = 0.f, b5 = 0.f, b6 = 0.f, b7 = 0.f;
  int i = 0;
  for (; i + 7 < len; i += 8) {
    int s0 = esrc[beg + i], s1 = esrc[beg + i + 1];
    int s2 = esrc[beg + i + 2], s3 = esrc[beg + i + 3];
    int s4 = esrc[beg + i + 4], s5 = esrc[beg + i + 5];
    int s6 = esrc[beg + i + 6], s7 = esrc[beg + i + 7];
    uint4 u0 = Hj[(size_t)s0 * 16];
    uint4 u1 = Hj[(size_t)s1 * 16];
    uint4 u2 = Hj[(size_t)s2 * 16];
    uint4 u3 = Hj[(size_t)s3 * 16];
    uint4 u4 = Hj[(size_t)s4 * 16];
    uint4 u5 = Hj[(size_t)s5 * 16];
    uint4 u6 = Hj[(size_t)s6 * 16];
    uint4 u7 = Hj[(size_t)s7 * 16];
    a0 += bf_lo(u0.x) + bf_lo(u1.x) + bf_lo(u2.x) + bf_lo(u3.x);
    a1 += bf_hi(u0.x) + bf_hi(u1.x) + bf_hi(u2.x) + bf_hi(u3.x);
    a2 += bf_lo(u0.y) + bf_lo(u1.y) + bf_lo(u2.y) + bf_lo(u3.y);
    a3 += bf_hi(u0.y) + bf_hi(u1.y) + bf_hi(u2.y) + bf_hi(u3.y);
    a4 += bf_lo(u0.z) + bf_lo(u1.z) + bf_lo(u2.z) + bf_lo(u3.z);
    a5 += bf_hi(u0.z) + bf_hi(u1.z) + bf_hi(u2.z) + bf_hi(u3.z);
    a6 += bf_lo(u0.w) + bf_lo(u1.w) + bf_lo(u2.w) + bf_lo(u3.w);
    a7 += bf_hi(u0.w) + bf_hi(u1.w) + bf_hi(u2.w) + bf_hi(u3.w);
    b0 += bf_lo(u4.x) + bf_lo(u5.x) + bf_lo(u6.x) + bf_lo(u7.x);
    b1 += bf_hi(u4.x) + bf_hi(u5.x) + bf_hi(u6.x) + bf_hi(u7.x);
    b2 += bf_lo(u4.y) + bf_lo(u5.y) + bf_lo(u6.y) + bf_lo(u7.y);
    b3 += bf_hi(u4.y) + bf_hi(u5.y) + bf_hi(u6.y) + bf_hi(u7.y);
    b4 += bf_lo(u4.z) + bf_lo(u5.z) + bf_lo(u6.z) + bf_lo(u7.z);
    b5 += bf_hi(u4.z) + bf_hi(u5.z) + bf_hi(u6.z) + bf_hi(u7.z);
    b6 += bf_lo(u4.w) + bf_lo(u5.w) + bf_lo(u6.w) + bf_lo(u7.w);
    b7 += bf_hi(u4.w) + bf_hi(u5.w) + bf_hi(u6.w) + bf_hi(u7.w);
  }
  for (; i < len; ++i) {
    uint4 u = Hj[(size_t)esrc[beg + i] * 16];
    a0 += bf_lo(u.x);
    a1 += bf_hi(u.x);
    a2 += bf_lo(u.y);
    a3 += bf_hi(u.y);
    a4 += bf_lo(u.z);
    a5 += bf_hi(u.z);
    a6 += bf_lo(u.w);
    a7 += bf_hi(u.w);
  }
  uint4 us = Hj[(size_t)n * 16];  // self (prescaled)
  a0 += b0 + bf_lo(us.x);
  a1 += b1 + bf_hi(us.x);
  a2 += b2 + bf_lo(us.y);
  a3 += b3 + bf_hi(us.y);
  a4 += b4 + bf_lo(us.z);
  a5 += b5 + bf_hi(us.z);
  a6 += b6 + bf_lo(us.w);
  a7 += b7 + bf_hi(us.w);
  float4 bv0 = ((const float4*)bias)[2 * j];
  float4 bv1 = ((const float4*)bias)[2 * j + 1];
  uint4 o;
  o.x = pack2(a0 * dn + bv0.x, a1 * dn + bv0.y);
  o.y = pack2(a2 * dn + bv0.z, a3 * dn + bv0.w);
  o.z = pack2(a4 * dn + bv1.x, a5 * dn + bv1.y);
  o.w = pack2(a6 * dn + bv1.z, a7 * dn + bv1.w);
  ((uint4*)outz)[(size_t)n * 16 + j] = o;
}

// ---------------- MFMA GEMM: Y[N][128] = bf16X[N][K] @ W[K][128] -> bf16 ----------------
template <int K, bool FUSE_NORM, bool DIS_SCALE, bool HAS_BIAS>
__global__ __launch_bounds__(256) void gemm_mfma(const ushort* __restrict__ X,
                                                 const ushort* __restrict__ Wt,
                                                 const float* __restrict__ bias,
                                                 const int* __restrict__ batch,
                                                 const float* __restrict__ mean,
                                                 const float* __restrict__ inv,
                                                 const float* __restrict__ disv,
                                                 ushort* __restrict__ Y, int N) {
  const int t = threadIdx.x;
  const int w = t >> 6;
  const int l = t & 63;
  const int lr = l & 15;   // A row / B-D col within tile
  const int lk = l >> 4;   // k-group 0..3 (also D row group)
  const int row0 = blockIdx.x * 64 + w * 16;
  const int arow = min(row0 + lr, N - 1);  // clamp: OOB rows produce discarded C rows
  int g = 0;
  if (FUSE_NORM) g = batch[arow];
  f32x4 acc[8];
#pragma unroll
  for (int i = 0; i < 8; ++i) acc[i] = (f32x4){0.f, 0.f, 0.f, 0.f};
#pragma unroll
  for (int k0 = 0; k0 < K; k0 += 32) {
    const int kbase = k0 + lk * 8;
    short8 a = *(const short8*)(X + (size_t)arow * K + kbase);
    if (FUSE_NORM) {
      const float* mp = mean + g * HID + kbase;
      const float* ip = inv + g * HID + kbase;
      short8 an;
#pragma unroll
      for (int j = 0; j < 8; ++j) {
        float f = __uint_as_float((uint)(ushort)a[j] << 16);
        f = fmaxf((f - mp[j]) * ip[j], 0.f);
        an[j] = (short)f2bf(f);
      }
      a = an;
    }
#pragma unroll
    for (int nf = 0; nf < 8; ++nf) {
      short8 b = *(const short8*)(Wt + (size_t)(nf * 16 + lr) * K + kbase);
      acc[nf] = __builtin_amdgcn_mfma_f32_16x16x32_bf16(a, b, acc[nf], 0, 0, 0);
    }
  }
#pragma unroll
  for (int r = 0; r < 4; ++r) {
    int grow = row0 + lk * 4 + r;
    if (grow < N) {
      float ds = DIS_SCALE ? disv[grow] : 1.f;
#pragma unroll
      for (int nf = 0; nf < 8; ++nf) {
        int col = nf * 16 + lr;
        float v = acc[nf][r];
        if (HAS_BIAS) v += bias[col];
        v *= ds;
        Y[(size_t)grow * HID + col] = f2bf(v);
      }
    }
  }
}

// ---------------- per-graph sum/sumsq (bf16 input, uint loads, REP replicas) ----------------
__global__ __launch_bounds__(256) void stats_pass(const ushort* __restrict__ G,
                                                  const int* __restrict__ batch,
                                                  float* __restrict__ gsum,
                                                  float* __restrict__ gsq, int N) {
  const int c2 = threadIdx.x & 63;   // uint slot: ch 2c2, 2c2+1
  const int sub = threadIdx.x >> 6;  // 0..3
  const int n0 = blockIdx.x * 64 + sub * 16;
  const int n1 = min(n0 + 16, N);
  const int roff = (blockIdx.x & (REP - 1)) * NH;  // replica
  float* gs = gsum + roff;
  float* gq = gsq + roff;
  const uint* Gj = (const uint*)G + c2;  // row stride 64 uints
  float s0 = 0.f, s1 = 0.f, q0 = 0.f, q1 = 0.f;
  int cur = -1;
  for (int n = n0; n < n1; ++n) {
    int g = batch[n];
    if (g != cur) {
      if (cur >= 0) {
        atomicAdd(&gs[cur * HID + 2 * c2], s0);
        atomicAdd(&gs[cur * HID + 2 * c2 + 1], s1);
        atomicAdd(&gq[cur * HID + 2 * c2], q0);
        atomicAdd(&gq[cur * HID + 2 * c2 + 1], q1);
      }
      cur = g;
      s0 = s1 = q0 = q1 = 0.f;
    }
    uint u = Gj[(size_t)n * 64];
    float v0 = bf_lo(u), v1 = bf_hi(u);
    s0 += v0;
    s1 += v1;
    q0 += v0 * v0;
    q1 += v1 * v1;
  }
  if (cur >= 0) {
    atomicAdd(&gs[cur * HID + 2 * c2], s0);
    atomicAdd(&gs[cur * HID + 2 * c2 + 1], s1);
    atomicAdd(&gq[cur * HID + 2 * c2], q0);
    atomicAdd(&gq[cur * HID + 2 * c2 + 1], q1);
  }
}

__global__ __launch_bounds__(256) void finalize_stats(const float* __restrict__ gsum,
                                                      const float* __restrict__ gsq,
                                                      const int* __restrict__ gstart,
                                                      float* __restrict__ mean,
                                                      float* __restrict__ inv) {
  int i = blockIdx.x * 256 + threadIdx.x;
  if (i >= NH) return;
  int g = i >> 7;
  float c = fmaxf((float)(gstart[g + 1] - gstart[g]), 1.f);
  float s = gsum[i] + gsum[i + NH] + gsum[i + 2 * NH] + gsum[i + 3 * NH];
  float q = gsq[i] + gsq[i + NH] + gsq[i + 2 * NH] + gsq[i + 3 * NH];
  float m = s / c;
  float v = q / c - m * m;
  mean[i] = m;
  inv[i] = rsqrtf(v + EPSN);
}

// ---------------- norm+relu+pool (bf16 input, uint loads, REP replicas) ----------------
__global__ __launch_bounds__(256) void norm_relu_pool(const ushort* __restrict__ G,
                                                      const int* __restrict__ batch,
                                                      const float* __restrict__ mean,
                                                      const float* __restrict__ inv,
                                                      float* __restrict__ pooled, int N) {
  const int c2 = threadIdx.x & 63;
  const int sub = threadIdx.x >> 6;
  const int n0 = blockIdx.x * 64 + sub * 16;
  const int n1 = min(n0 + 16, N);
  float* pl = pooled + (blockIdx.x & (REP - 1)) * NH;
  const uint* Gj = (const uint*)G + c2;
  float p0 = 0.f, p1 = 0.f;
  int cur = -1;
  float2 mv = {0.f, 0.f}, iv = {0.f, 0.f};
  for (int n = n0; n < n1; ++n) {
    int g = batch[n];
    if (g != cur) {
      if (cur >= 0) {
        atomicAdd(&pl[cur * HID + 2 * c2], p0);
        atomicAdd(&pl[cur * HID + 2 * c2 + 1], p1);
      }
      cur = g;
      p0 = p1 = 0.f;
      mv = ((const float2*)mean)[g * 64 + c2];
      iv = ((const float2*)inv)[g * 64 + c2];
    }
    uint u = Gj[(size_t)n * 64];
    p0 += fmaxf((bf_lo(u) - mv.x) * iv.x, 0.f);
    p1 += fmaxf((bf_hi(u) - mv.y) * iv.y, 0.f);
  }
  if (cur >= 0) {
    atomicAdd(&pl[cur * HID + 2 * c2], p0);
    atomicAdd(&pl[cur * HID + 2 * c2 + 1], p1);
  }
}

// ---------------- final head ----------------
__global__ __launch_bounds__(256) void final_head(const float* __restrict__ pooled_sum,
                                                  const int* __restrict__ gstart,
                                                  const float* __restrict__ gamma,
                                                  const float* __restrict__ beta,
                                                  const float* __restrict__ fcW,
                                                  const float* __restrict__ fcb,
                                                  float* __restrict__ out) {
  __shared__ float P[NGRAPH][HID];
  __shared__ float zs[HID], zb[HID];
  int t = threadIdx.x;
  for (int i = t; i < NH; i += 256) {
    int g = i >> 7;
    float c = fmaxf((float)(gstart[g + 1] - gstart[g]), 1.f);
    float s = pooled_sum[i] + pooled_sum[i + NH] + pooled_sum[i + 2 * NH] +
              pooled_sum[i + 3 * NH];
    P[g][i & 127] = s / c;
  }
  __syncthreads();
  if (t < HID) {
    float m = 0.f;
    for (int g = 0; g < NGRAPH; ++g) m += P[g][t];
    m *= (1.f / NGRAPH);
    float v = 0.f;
    for (int g = 0; g < NGRAPH; ++g) {
      float d = P[g][t] - m;
      v += d * d;
    }
    v *= (1.f / NGRAPH);
    float sc = rsqrtf(v + EPSN) * gamma[t];
    zs[t] = sc;
    zb[t] = beta[t] - m * sc;
  }
  __syncthreads();
  if (t < NGRAPH * 2) {
    int g = t >> 1, k = t & 1;
    float acc = fcb[k];
    for (int c = 0; c < HID; ++c) {
      float z = P[g][c] * zs[c] + zb[c];
      acc += z * fcW[c * 2 + k];
    }
    out[t] = acc;
  }
}

extern "C" void kernel_launch(void* const* d_in, const int* in_sizes, int n_in,
                              void* d_out, int out_size, void* d_ws, size_t ws_size,
                              hipStream_t stream) {
  const float* x = (const float*)d_in[0];
  const int* ei = (const int*)d_in[1];     // int32
  const int* batch = (const int*)d_in[2];  // int32 (sorted)
  const float* W1 = (const float*)d_in[3];
  const float* b1 = (const float*)d_in[4];
  const float* W2 = (const float*)d_in[5];
  const float* b2 = (const float*)d_in[6];
  const float* gamma = (const float*)d_in[7];
  const float* beta = (const float*)d_in[8];
  const float* fcW = (const float*)d_in[9];
  const float* fcb = (const float*)d_in[10];
  float* out = (float*)d_out;

  const int N = in_sizes[2];
  const int E = in_sizes[1] / 2;
  const int* srcp = ei;
  const int* dstp = ei + E;
  const int NB = (N + 255) >> BSHIFT;       // buckets (<=512 for N<=131072)
  const int cap = 2 * (E / NB) + 256;       // per-bucket capacity (~64 sigma margin)

  // workspace layout (floats)
  float* ws = (float*)d_ws;
  size_t off = 0;
  auto alloc = [&](size_t n) {
    float* p = ws + off;
    off += (n + 127) & ~(size_t)127;
    return p;
  };
  int* row_beg = (int*)alloc(N);
  int* row_end = (int*)alloc(N);
  int* esrc = (int*)alloc((size_t)NB * cap);
  // records (NB*cap uints) region, later reused as xs (bf16 N x 64 = N*32 uints)
  size_t recsz = ((size_t)NB * cap > (size_t)N * 32 ? (size_t)NB * cap : (size_t)N * 32);
  float* recbuf = alloc(recsz);
  float* dis = alloc(N);
  float* y1b = alloc((size_t)N * 32);   // bf16 N x 64
  float* h1b = alloc((size_t)N * 64);   // bf16 N x 128
  float* h2b = alloc((size_t)N * 64);   // bf16 N x 128
  float* zb_ = alloc((size_t)N * 64);   // bf16 N x 128
  float* w1tb = alloc(128 * 64 / 2);    // bf16 128x64 (col-major Wt)
  float* w2tb = alloc(128 * 128 / 2);   // bf16 128x128
  int* gstart = (int*)alloc(NGRAPH + 1);
  float* zero0 = ws + off;              // zeroed region start
  int* gcursor = (int*)alloc(NBMAX);    // relative cursors (must be zeroed)
  float* gsum1 = alloc(NH * REP);
  float* gsq1 = alloc(NH * REP);
  float* gsum2 = alloc(NH * REP);
  float* gsq2 = alloc(NH * REP);
  float* pooled = alloc(NH * REP);
  size_t zero_bytes = (size_t)((ws + off) - zero0) * sizeof(float);
  float* mean1 = alloc(NH);
  float* inv1 = alloc(NH);
  float* mean2 = alloc(NH);
  float* inv2 = alloc(NH);

  uint* records = (uint*)recbuf;
  ushort* xs = (ushort*)recbuf;  // alias: records dead after build_csr
  ushort* y1 = (ushort*)y1b;
  ushort* h1 = (ushort*)h1b;
  ushort* h2s = (ushort*)h2b;
  ushort* z = (ushort*)zb_;
  ushort* w1t = (ushort*)w1tb;
  ushort* w2t = (ushort*)w2tb;

  const int nblkN = (N + 255) / 256;
  const int nblkE4k = (E + 4095) / 4096;

  hipMemsetAsync(zero0, 0, zero_bytes, stream);

  // weight transposes + graph segments + padded CSR build
  wt_both<<<(128 * 64 + 128 * 128 + 255) / 256, 256, 0, stream>>>(W1, W2, w1t, w2t);
  graph_starts<<<nblkN, 256, 0, stream>>>(batch, gstart, N);
  bin_edges<<<nblkE4k, 256, 0, stream>>>(srcp, dstp, gcursor, records, E, NB, cap);
  build_csr<<<NB, 256, 0, stream>>>(records, gcursor, row_beg, row_end, dis, esrc, N, cap);

  const int aggBlocks = ((N + 3) / 4 + 3) / 4;  // 4 nodes per wave, 4 waves/block
  const int gemmBlocks = (N + 63) / 64;         // 64 rows per block
  const int nrmBlocks = (N + 63) / 64;          // stats/pool: 64 nodes per block

  // ---- layer 1: xs = bf16(x*dis); y1 = A-hat x (bf16); h1 = y1 @ W1 + b1 (bf16) ----
  xscale_bf16<<<(N * 16 + 255) / 256, 256, 0, stream>>>(x, dis, xs, N * 16);
  aggregate64<<<aggBlocks, 256, 0, stream>>>(xs, row_beg, row_end, esrc, dis, y1, N);
  gemm_mfma<64, false, false, true><<<gemmBlocks, 256, 0, stream>>>(
      y1, w1t, b1, nullptr, nullptr, nullptr, nullptr, h1, N);
  stats_pass<<<nrmBlocks, 256, 0, stream>>>(h1, batch, gsum1, gsq1, N);
  finalize_stats<<<(NH + 255) / 256, 256, 0, stream>>>(gsum1, gsq1, gstart, mean1, inv1);

  // ---- layer 2: h2s = bf16(relu(norm(h1)) @ W2 * dis); z = A-hat h2 + b2 (bf16) ----
  gemm_mfma<128, true, true, false><<<gemmBlocks, 256, 0, stream>>>(
      h1, w2t, nullptr, batch, mean1, inv1, dis, h2s, N);
  aggregate128<<<aggBlocks, 256, 0, stream>>>(h2s, row_beg, row_end, esrc, dis, b2, z, N);
  stats_pass<<<nrmBlocks, 256, 0, stream>>>(z, batch, gsum2, gsq2, N);
  finalize_stats<<<(NH + 255) / 256, 256, 0, stream>>>(gsum2, gsq2, gstart, mean2, inv2);
  norm_relu_pool<<<nrmBlocks, 256, 0, stream>>>(z, batch, mean2, inv2, pooled, N);

  // ---- head ----
  final_head<<<1, 256, 0, stream>>>(pooled, gstart, gamma, beta, fcW, fcb, out);
}